// Round 1
// baseline (1627.358 us; speedup 1.0000x reference)
//
#include <hip/hip_runtime.h>
#include <hip/hip_bf16.h>

typedef __bf16 bf16;
typedef __bf16 bf16x8 __attribute__((ext_vector_type(8)));
typedef float floatx4 __attribute__((ext_vector_type(4)));

#define MFMA16(a, b, c) __builtin_amdgcn_mfma_f32_16x16x32_bf16((a), (b), (c), 0, 0, 0)

static constexpr int Cn = 256, HWn = 65536, Wpix = 256;
static constexpr int NWIN = 8192;  // 8 * 32 * 32
static constexpr int XP = 264;     // x / AO pitch (256 + 8): bank step 4 -> 2-way (free)
static constexpr int QP = 72;      // Q/K/V/P pitch (64 + 8): 16B-aligned rows, bank step 4

__global__ void convert_weights_kernel(const float* __restrict__ qkv_w,
                                       const float* __restrict__ proj_w,
                                       bf16* __restrict__ qkv_wb,
                                       bf16* __restrict__ proj_wb) {
    int i = blockIdx.x * 256 + threadIdx.x;
    if (i < 768 * 256) qkv_wb[i] = (bf16)qkv_w[i];
    if (i < 256 * 256) proj_wb[i] = (bf16)proj_w[i];
}

// One block per 8x8 window. 16 waves. Fused: qkv-GEMM -> window attention -> proj.
__global__ __launch_bounds__(1024) void win_attn_kernel(
    const float* __restrict__ x,
    const float* __restrict__ qkv_b,
    const float* __restrict__ proj_b,
    const bf16* __restrict__ qkv_wb,   // [768][256] row-major bf16
    const bf16* __restrict__ proj_wb,  // [256][256] row-major bf16
    float* __restrict__ out)
{
    // bufA: xw[t][c] (64*264=16896) then P[h][n][m] (4*64*72=18432)
    // bufB: Q_t[h][n][d] then AO[n][c] (64*264=16896)
    // bufC: K_t[h][m][d]
    // bufD: V_cm[h][d][m]
    __shared__ __align__(16) bf16 bufA[4 * 64 * QP];
    __shared__ __align__(16) bf16 bufB[4 * 64 * QP];
    __shared__ __align__(16) bf16 bufC[4 * 64 * QP];
    __shared__ __align__(16) bf16 bufD[4 * 64 * QP];

    // XCD swizzle: adjacent windows (same row) land on the same XCD for L2 locality
    int p = blockIdx.x;
    int wid = (p & 7) * (NWIN / 8) + (p >> 3);
    int b = wid >> 10;
    int rem = wid & 1023;
    int hn = rem >> 5, wn = rem & 31;
    int h0 = hn * 8, w0 = wn * 8;

    int tid = threadIdx.x;
    int wave = tid >> 6;
    int lane = tid & 63;
    int quad = lane >> 4;
    int l15 = lane & 15;

    // ---- Phase 0: load x window -> xw[t][c] bf16 (token t = r*8+k) ----
    {
        const float* xb = x + (size_t)b * Cn * HWn;
#pragma unroll
        for (int it = 0; it < 2; ++it) {
            int idx = tid + it * 1024;  // [0, 2048): (c, r)
            int c = idx >> 3, r = idx & 7;
            const float* g = xb + (size_t)c * HWn + (h0 + r) * Wpix + w0;
            float4 v0 = *(const float4*)g;
            float4 v1 = *(const float4*)(g + 4);
            bf16* dst = bufA + (r * 8) * XP + c;
            dst[0 * XP] = (bf16)v0.x; dst[1 * XP] = (bf16)v0.y;
            dst[2 * XP] = (bf16)v0.z; dst[3 * XP] = (bf16)v0.w;
            dst[4 * XP] = (bf16)v1.x; dst[5 * XP] = (bf16)v1.y;
            dst[6 * XP] = (bf16)v1.z; dst[7 * XP] = (bf16)v1.w;
        }
    }
    __syncthreads();

    // ---- Phase 1: QKV GEMM. D[px][o] = sum_c xw[px][c] * qkv_w[o][c] + qkv_b[o] ----
    // wave handles o-tiles ot = wave*3 + j (j=0..2), all 4 px-tiles. 12 acc tiles/wave.
    {
        floatx4 acc[3][4];
#pragma unroll
        for (int j = 0; j < 3; ++j)
#pragma unroll
            for (int t = 0; t < 4; ++t) acc[j][t] = (floatx4){0.f, 0.f, 0.f, 0.f};
        int otbase = wave * 3;
#pragma unroll
        for (int c0 = 0; c0 < 256; c0 += 32) {
            bf16x8 afr[4];
#pragma unroll
            for (int t = 0; t < 4; ++t)
                afr[t] = *(const bf16x8*)&bufA[(t * 16 + l15) * XP + c0 + quad * 8];
#pragma unroll
            for (int j = 0; j < 3; ++j) {
                int o = (otbase + j) * 16 + l15;
                bf16x8 bfr = *(const bf16x8*)&qkv_wb[o * 256 + c0 + quad * 8];
#pragma unroll
                for (int t = 0; t < 4; ++t)
                    acc[j][t] = MFMA16(afr[t], bfr, acc[j][t]);
            }
        }
        // Scatter to Q/K/V. IMPORTANT: reference splits 768 channels HEAD-MAJOR:
        // head h = o/192; within-head j = o%192: Q=j<64, K=64..128, V=128..192.
#pragma unroll
        for (int j = 0; j < 3; ++j) {
            int ot = otbase + j;           // [0,48), 16 channels each; never straddles
            int hh = ot / 12;              // head
            int j12 = ot - hh * 12;
            int type = j12 >> 2;           // 0=Q, 1=K, 2=V
            int d = (j12 & 3) * 16 + l15;  // channel within head-part
            float bias = qkv_b[ot * 16 + l15];
#pragma unroll
            for (int t = 0; t < 4; ++t) {
#pragma unroll
                for (int r = 0; r < 4; ++r) {
                    int px = t * 16 + quad * 4 + r;
                    bf16 v = (bf16)(acc[j][t][r] + bias);
                    if (type == 0)      bufB[(hh * 64 + px) * QP + d] = v;  // Q_t[n][d]
                    else if (type == 1) bufC[(hh * 64 + px) * QP + d] = v;  // K_t[m][d]
                    else                bufD[(hh * 64 + d) * QP + px] = v;  // V_cm[d][m]
                }
            }
        }
    }
    __syncthreads();

    // ---- Phase 2: attention. wave -> (head, 16-row block) ----
    floatx4 oacc[4];
    {
        int hh = wave >> 2;
        int rb = wave & 3;
        int n0 = rb * 16;
        const bf16* Q = bufB + hh * 64 * QP;
        const bf16* K = bufC + hh * 64 * QP;
        const bf16* V = bufD + hh * 64 * QP;
        bf16* P = bufA + hh * 64 * QP;  // overlays xw (dead after phase 1 + barrier)

        floatx4 sacc[4];
#pragma unroll
        for (int mt = 0; mt < 4; ++mt) sacc[mt] = (floatx4){0.f, 0.f, 0.f, 0.f};
#pragma unroll
        for (int d0 = 0; d0 < 64; d0 += 32) {
            bf16x8 aq = *(const bf16x8*)&Q[(n0 + l15) * QP + d0 + quad * 8];
#pragma unroll
            for (int mt = 0; mt < 4; ++mt) {
                bf16x8 bk = *(const bf16x8*)&K[(mt * 16 + l15) * QP + d0 + quad * 8];
                sacc[mt] = MFMA16(aq, bk, sacc[mt]);
            }
        }
        // online-free softmax (full 64 cols resident): rows n = n0 + quad*4 + r
        const float scale = 0.125f;  // dh^-0.5
#pragma unroll
        for (int r = 0; r < 4; ++r) {
            float m = -1e30f;
#pragma unroll
            for (int mt = 0; mt < 4; ++mt) m = fmaxf(m, sacc[mt][r]);
#pragma unroll
            for (int s = 1; s < 16; s <<= 1) m = fmaxf(m, __shfl_xor(m, s, 64));
            float sum = 0.f;
#pragma unroll
            for (int mt = 0; mt < 4; ++mt) {
                float e = __expf((sacc[mt][r] - m) * scale);
                sacc[mt][r] = e;
                sum += e;
            }
#pragma unroll
            for (int s = 1; s < 16; s <<= 1) sum += __shfl_xor(sum, s, 64);
            float rs = 1.0f / sum;
#pragma unroll
            for (int mt = 0; mt < 4; ++mt)
                P[(n0 + quad * 4 + r) * QP + mt * 16 + l15] = (bf16)(sacc[mt][r] * rs);
        }
        // O = P * V  (wave reads only its own P rows; same-wave RAW handled by lgkmcnt)
#pragma unroll
        for (int dt = 0; dt < 4; ++dt) oacc[dt] = (floatx4){0.f, 0.f, 0.f, 0.f};
#pragma unroll
        for (int m0 = 0; m0 < 64; m0 += 32) {
            bf16x8 ap = *(const bf16x8*)&P[(n0 + l15) * QP + m0 + quad * 8];
#pragma unroll
            for (int dt = 0; dt < 4; ++dt) {
                bf16x8 bv = *(const bf16x8*)&V[(dt * 16 + l15) * QP + m0 + quad * 8];
                oacc[dt] = MFMA16(ap, bv, oacc[dt]);
            }
        }
    }
    __syncthreads();  // all waves done reading Q_t -> bufB reusable as AO

    // ---- Phase 3: O -> AO[n][c], c = head*64 + d (head-major over C=256) ----
    {
        int hh = wave >> 2;
        int rb = wave & 3;
        int n0 = rb * 16;
#pragma unroll
        for (int dt = 0; dt < 4; ++dt)
#pragma unroll
            for (int r = 0; r < 4; ++r)
                bufB[(n0 + quad * 4 + r) * XP + hh * 64 + dt * 16 + l15] = (bf16)oacc[dt][r];
    }
    __syncthreads();

    // ---- Phase 4: proj. D[o2][px] = sum_c proj_w[o2][c] * AO[px][c] + proj_b ----
    {
        floatx4 pacc[4];
#pragma unroll
        for (int t = 0; t < 4; ++t) pacc[t] = (floatx4){0.f, 0.f, 0.f, 0.f};
        int o2base = wave * 16;
#pragma unroll
        for (int c0 = 0; c0 < 256; c0 += 32) {
            bf16x8 aw = *(const bf16x8*)&proj_wb[(o2base + l15) * 256 + c0 + quad * 8];
#pragma unroll
            for (int t = 0; t < 4; ++t) {
                bf16x8 bb = *(const bf16x8*)&bufB[(t * 16 + l15) * XP + c0 + quad * 8];
                pacc[t] = MFMA16(aw, bb, pacc[t]);
            }
        }
        float* ob = out + (size_t)b * Cn * HWn;
#pragma unroll
        for (int t = 0; t < 4; ++t) {
#pragma unroll
            for (int r = 0; r < 4; ++r) {
                int o2 = o2base + quad * 4 + r;
                int px = t * 16 + l15;
                ob[(size_t)o2 * HWn + (h0 + (px >> 3)) * Wpix + w0 + (px & 7)] =
                    pacc[t][r] + proj_b[o2];
            }
        }
    }
}

extern "C" void kernel_launch(void* const* d_in, const int* in_sizes, int n_in,
                              void* d_out, int out_size, void* d_ws, size_t ws_size,
                              hipStream_t stream) {
    const float* x      = (const float*)d_in[0];
    const float* qkv_w  = (const float*)d_in[1];
    const float* qkv_b  = (const float*)d_in[2];
    const float* proj_w = (const float*)d_in[3];
    const float* proj_b = (const float*)d_in[4];
    float* out = (float*)d_out;

    bf16* qkv_wb  = (bf16*)d_ws;                 // 768*256 bf16
    bf16* proj_wb = qkv_wb + 768 * 256;          // 256*256 bf16 (total 512 KB + change)

    convert_weights_kernel<<<768, 256, 0, stream>>>(qkv_w, proj_w, qkv_wb, proj_wb);
    win_attn_kernel<<<NWIN, 1024, 0, stream>>>(x, qkv_b, proj_b, qkv_wb, proj_wb, out);
}